// Round 7
// baseline (290.267 us; speedup 1.0000x reference)
//
#include <hip/hip_runtime.h>

typedef float f4 __attribute__((ext_vector_type(4)));
typedef __attribute__((ext_vector_type(4))) float f32x4;
typedef __attribute__((ext_vector_type(8))) short bf8;

__device__ __forceinline__ float bf2f(unsigned hu16) {
    union { unsigned u; float f; } v; v.u = hu16 << 16;
    return v.f;
}
// truncation split: hi = top 16 bits, lo = trunc(v - hi); net ~2^-16 relative.
__device__ __forceinline__ void split2t(float v, ushort& hi, ushort& lo) {
    union { float f; unsigned u; } a; a.f = v;
    unsigned hu = a.u & 0xFFFF0000u;
    hi = (ushort)(hu >> 16);
    union { unsigned u; float f; } hv; hv.u = hu;
    union { float f; unsigned u; } lres; lres.f = v - hv.f;
    lo = (ushort)(lres.u >> 16);
}
__device__ __forceinline__ ushort ftrunc_bf(float f) {
    union { float f; unsigned u; } v; v.f = f;
    return (ushort)(v.u >> 16);
}

__global__ __launch_bounds__(256, 3)
void avif_mfma7(const float* __restrict__ x, const float* __restrict__ twm,
                const float* __restrict__ w1, const float* __restrict__ b1,
                const float* __restrict__ w2, const float* __restrict__ b2,
                float* __restrict__ out)
{
    // XOR-swizzled planes, granule = 8 ushorts (16B):
    // element (px, c) -> row px, ushort idx = swz(px, c>>3)*8 + (c&7)
    // swz(px, g) = g ^ (px&7) ^ (((px>>3)&1)<<2)
    __shared__ ushort ysh[128][64];   // Y hi
    __shared__ ushort ysl[128][64];   // Y lo
    __shared__ ushort hsh[128][64];   // H hi (48 KB -> 3 blocks/CU)

    const int t = threadIdx.x;
    const int bid = blockIdx.x;
    const int wtp = bid & 15;          // tile pair: wt = 2*wtp, 2*wtp+1
    const int hb  = (bid >> 4) & 63;
    const int b   = bid >> 10;

    const int wv   = t >> 6;
    const int lane = t & 63;
    const int li   = lane & 15;
    const int lg   = lane >> 4;
    const int l7   = li & 7;
    const int lb3  = (li >> 3) << 2;

    // phase-1 identity: lane pair (2m,2m+1) shares one (c,blk);
    // row-partition for M (each lane owns 4 P-rows), q-partition for Y cols.
    const int pid = t >> 1;            // 0..127
    const int h2  = t & 1;
    const int c   = pid & 63, blk = pid >> 6;
    const int r0  = 4 * h2;            // my P/M row half
    const int Q0  = 4 * h2;            // my Y column half
    const float* tB = twm + c * 64;
    const float* xT0 = x + ((size_t)(b * 64 + c) * 512 + hb * 8 + r0) * 512
                         + (2 * wtp) * 16 + blk * 8;
    const float* xT1 = xT0 + 16;
    const int cg = c >> 3, c7 = c & 7;

    // ---- issue tile-0 x loads (8 f4: my 4 rows x 2 halves) ----
    f4 Pr0[8];
#pragma unroll
    for (int i = 0; i < 4; ++i) {
        Pr0[2 * i]     = *(const f4*)(xT0 + i * 512);
        Pr0[2 * i + 1] = *(const f4*)(xT0 + i * 512 + 4);
    }
    // ---- issue tile-1 x loads early: drain under tile-0 compute ----
    f4 Pr1[8];
#pragma unroll
    for (int i = 0; i < 4; ++i) {
        Pr1[2 * i]     = *(const f4*)(xT1 + i * 512);
        Pr1[2 * i + 1] = *(const f4*)(xT1 + i * 512 + 4);
    }

    // ---- transform: P(8x8, row-split across lane pair) -> Y split-bf16 LDS ----
    auto transform = [&](const f4 (&Pr)[8]) {
        float M[4][8];                 // my 4 rows, all 8 q
#pragma unroll
        for (int q = 0; q < 8; ++q) {
            f4 Ta = *(const f4*)(tB + q * 8);
            f4 Td = *(const f4*)(tB + q * 8 + 4);
#pragma unroll
            for (int i = 0; i < 4; ++i) {
                float s = Pr[2 * i][0] * Ta[0];
                s = fmaf(Pr[2 * i][1], Ta[1], s);
                s = fmaf(Pr[2 * i][2], Ta[2], s);
                s = fmaf(Pr[2 * i][3], Ta[3], s);
                s = fmaf(Pr[2 * i + 1][0], Td[0], s);
                s = fmaf(Pr[2 * i + 1][1], Td[1], s);
                s = fmaf(Pr[2 * i + 1][2], Td[2], s);
                s = fmaf(Pr[2 * i + 1][3], Td[3], s);
                M[i][q] = s;
            }
        }
        // exchange: partner's 4 rows at MY q-range (static indices + cndmask)
        float MO[4][4];
#pragma unroll
        for (int i = 0; i < 4; ++i)
#pragma unroll
            for (int qq = 0; qq < 4; ++qq) {
                float send = h2 ? M[i][qq] : M[i][4 + qq];
                MO[i][qq] = __shfl_xor(send, 1);
            }
        float R0[4][4], R4[4][4];      // rows 0-3 / 4-7 at my q
#pragma unroll
        for (int i = 0; i < 4; ++i)
#pragma unroll
            for (int qq = 0; qq < 4; ++qq) {
                R0[i][qq] = h2 ? MO[i][qq] : M[i][qq];
                R4[i][qq] = h2 ? M[i][4 + qq] : MO[i][qq];
            }
        // stage 2: Y[p][q] for my 4 q, all 8 p; T rows streamed (L1-hot)
#pragma unroll
        for (int p = 0; p < 8; ++p) {
            f4 a = *(const f4*)(tB + p * 8);
            f4 d = *(const f4*)(tB + p * 8 + 4);
            const int px0 = p * 16 + blk * 8;
#pragma unroll
            for (int qq = 0; qq < 4; ++qq) {
                const int q = Q0 + qq;
                float s = a[0] * R0[0][qq];
                s = fmaf(a[1], R0[1][qq], s);
                s = fmaf(a[2], R0[2][qq], s);
                s = fmaf(a[3], R0[3][qq], s);
                s = fmaf(d[0], R4[0][qq], s);
                s = fmaf(d[1], R4[1][qq], s);
                s = fmaf(d[2], R4[2][qq], s);
                s = fmaf(d[3], R4[3][qq], s);
                ushort hi, lo; split2t(s, hi, lo);
                const int idx = ((cg ^ q ^ (blk << 2)) << 3) | c7;
                ysh[px0 + q][idx] = hi;
                ysl[px0 + q][idx] = lo;
            }
        }
    };

    transform(Pr0);

    // ---- W fragments (hi+lo): loaded after transform to bound reg pressure ----
    bf8 w1h[2], w1l[2], w2h[2], w2l[2];
    {
        const float* p1 = w1 + (16 * wv + li) * 64 + lg * 8;
        const float* p2 = w2 + (16 * wv + li) * 64 + lg * 8;
#pragma unroll
        for (int kk = 0; kk < 2; ++kk) {
            f4 a = *(const f4*)(p1 + kk * 32);
            f4 d = *(const f4*)(p1 + kk * 32 + 4);
            bf8 fh, fl; ushort hi, lo;
#pragma unroll
            for (int q = 0; q < 4; ++q) {
                split2t(a[q], hi, lo); fh[q] = (short)hi; fl[q] = (short)lo;
                split2t(d[q], hi, lo); fh[4 + q] = (short)hi; fl[4 + q] = (short)lo;
            }
            w1h[kk] = fh; w1l[kk] = fl;
            a = *(const f4*)(p2 + kk * 32);
            d = *(const f4*)(p2 + kk * 32 + 4);
#pragma unroll
            for (int q = 0; q < 4; ++q) {
                split2t(a[q], hi, lo); fh[q] = (short)hi; fl[q] = (short)lo;
                split2t(d[q], hi, lo); fh[4 + q] = (short)hi; fl[4 + q] = (short)lo;
            }
            w2h[kk] = fh; w2l[kk] = fl;
        }
    }
    const int o0 = 16 * wv + 4 * lg;
    const f4 b1v = *(const f4*)(b1 + o0);
    const float b2s = b2[16 * wv + li];
    const int sg0 = ((lg       ^ l7 ^ lb3) << 3);
    const int sg1 = (((4 + lg) ^ l7 ^ lb3) << 3);
    const int go  = o0 >> 3, co = 4 * (lg & 1);
    const int ch  = 16 * wv + li;
    const int cgE = ch >> 3, c7E = li & 7;

    // ---- GEMM1 + GEMM2 + epilogue for one tile ----
    auto do_tile = [&](int wt) {
        f32x4 acc[8];
#pragma unroll
        for (int j = 0; j < 8; ++j) acc[j] = (f32x4){0.f, 0.f, 0.f, 0.f};
#pragma unroll
        for (int j = 0; j < 8; ++j) {
            const int row = 16 * j + li;
            bf8 bh0 = *(const bf8*)&ysh[row][sg0];
            bf8 bl0 = *(const bf8*)&ysl[row][sg0];
            bf8 bh1 = *(const bf8*)&ysh[row][sg1];
            bf8 bl1 = *(const bf8*)&ysl[row][sg1];
            acc[j] = __builtin_amdgcn_mfma_f32_16x16x32_bf16(w1h[0], bh0, acc[j], 0, 0, 0);
            acc[j] = __builtin_amdgcn_mfma_f32_16x16x32_bf16(w1h[0], bl0, acc[j], 0, 0, 0);
            acc[j] = __builtin_amdgcn_mfma_f32_16x16x32_bf16(w1l[0], bh0, acc[j], 0, 0, 0);
            acc[j] = __builtin_amdgcn_mfma_f32_16x16x32_bf16(w1h[1], bh1, acc[j], 0, 0, 0);
            acc[j] = __builtin_amdgcn_mfma_f32_16x16x32_bf16(w1h[1], bl1, acc[j], 0, 0, 0);
            acc[j] = __builtin_amdgcn_mfma_f32_16x16x32_bf16(w1l[1], bh1, acc[j], 0, 0, 0);
        }
#pragma unroll
        for (int j = 0; j < 8; ++j) {
            const int px = 16 * j + li;
            const int idx = ((go ^ l7 ^ lb3) << 3) + co;
            unsigned h0 = ftrunc_bf(fmaxf(acc[j][0] + b1v[0], 0.f));
            unsigned h1 = ftrunc_bf(fmaxf(acc[j][1] + b1v[1], 0.f));
            unsigned hh2 = ftrunc_bf(fmaxf(acc[j][2] + b1v[2], 0.f));
            unsigned h3 = ftrunc_bf(fmaxf(acc[j][3] + b1v[3], 0.f));
            *(unsigned*)&hsh[px][idx]     = h0 | (h1 << 16);
            *(unsigned*)&hsh[px][idx + 2] = hh2 | (h3 << 16);
        }
        __syncthreads();
        // GEMM2 swapped: D[px][channel] -> f4 coalesced stores
#pragma unroll
        for (int j = 0; j < 8; ++j) acc[j] = (f32x4){0.f, 0.f, 0.f, 0.f};
#pragma unroll
        for (int j = 0; j < 8; ++j) {
            const int row = 16 * j + li;
            bf8 ah0 = *(const bf8*)&hsh[row][sg0];
            bf8 ah1 = *(const bf8*)&hsh[row][sg1];
            acc[j] = __builtin_amdgcn_mfma_f32_16x16x32_bf16(ah0, w2h[0], acc[j], 0, 0, 0);
            acc[j] = __builtin_amdgcn_mfma_f32_16x16x32_bf16(ah0, w2l[0], acc[j], 0, 0, 0);
            acc[j] = __builtin_amdgcn_mfma_f32_16x16x32_bf16(ah1, w2h[1], acc[j], 0, 0, 0);
            acc[j] = __builtin_amdgcn_mfma_f32_16x16x32_bf16(ah1, w2l[1], acc[j], 0, 0, 0);
        }
        float* oB = out + ((size_t)(b * 64) + ch) * 262144
                    + (size_t)(hb * 8) * 512 + wt * 16 + 4 * lg;
#pragma unroll
        for (int j = 0; j < 8; ++j) {
            f4 r;
#pragma unroll
            for (int r4 = 0; r4 < 4; ++r4) {
                const int pc = 4 * lg + r4;
                const int px = 16 * j + pc;
                const int idx = ((cgE ^ (pc & 7) ^ (((pc >> 3) & 1) << 2)) << 3) | c7E;
                float yv = bf2f((unsigned)ysh[px][idx]) + bf2f((unsigned)ysl[px][idx]);
                float z = acc[j][r4] + b2s;
                float g = __builtin_amdgcn_rcpf(1.f + __expf(-z));
                r[r4] = yv * g;
            }
            *(f4*)(oB + (size_t)j * 512) = r;
        }
    };

    __syncthreads();
    do_tile(2 * wtp);
    __syncthreads();          // protect ysh/ysl/hsh reuse
    transform(Pr1);           // x already in flight since prologue
    __syncthreads();
    do_tile(2 * wtp + 1);
}

extern "C" void kernel_launch(void* const* d_in, const int* in_sizes, int n_in,
                              void* d_out, int out_size, void* d_ws, size_t ws_size,
                              hipStream_t stream) {
    (void)in_sizes; (void)n_in; (void)out_size; (void)d_ws; (void)ws_size;
    const float* x   = (const float*)d_in[0];
    const float* twm = (const float*)d_in[1];
    const float* w1  = (const float*)d_in[2];
    const float* b1  = (const float*)d_in[3];
    const float* w2  = (const float*)d_in[4];
    const float* b2  = (const float*)d_in[5];
    float* out = (float*)d_out;

    avif_mfma7<<<dim3(4 * 64 * 16), dim3(256), 0, stream>>>(x, twm, w1, b1, w2, b2, out);
}

// Round 8
// 232.551 us; speedup vs baseline: 1.2482x; 1.2482x over previous
//
#include <hip/hip_runtime.h>

typedef float f4 __attribute__((ext_vector_type(4)));
typedef __attribute__((ext_vector_type(4))) float f32x4;
typedef _Float16 h8 __attribute__((ext_vector_type(8)));

__global__ __launch_bounds__(256, 5)
void avif_mfma8(const float* __restrict__ x, const float* __restrict__ twm,
                const float* __restrict__ w1, const float* __restrict__ b1,
                const float* __restrict__ w2, const float* __restrict__ b2,
                float* __restrict__ out)
{
    // fp16 planes, XOR-swizzled on the 8-ushort (16B) granule:
    // element (px, c) -> row px, ushort idx = swz*8 + (c&7)
    // swz = (c>>3) ^ (px&7) ^ (((px>>3)&1)<<2)
    __shared__ ushort ysf[128][64];   // Y fp16
    __shared__ ushort hsf[128][64];   // H fp16   (32 KB total -> 5 blocks/CU)

    const int t = threadIdx.x;
    const int bid = blockIdx.x;
    // XCD-friendly decode
    const int b3 = (bid >> 3) & 1;
    const int u  = ((bid >> 4) << 3) | (bid & 7);
    const int wt = ((u & 15) << 1) | b3;   // 0..31
    const int hb = (u >> 4) & 63;          // 0..63
    const int b  = u >> 10;                // 0..3

    const int wv   = t >> 6;
    const int lane = t & 63;
    const int li   = lane & 15;
    const int lg   = lane >> 4;
    const int l7   = li & 7;
    const int lb3  = (li >> 3) << 2;

    // ---- phase 1: lane pair shares one (c,blk); q-partitioned (each lane
    // owns 4 Y COLUMNS q = 4*h2..4*h2+3, all 8 rows). M is [8][4]. ----
    {
        const int pid = t >> 1;          // 0..127
        const int h2  = t & 1;
        const int c   = pid & 63, blk = pid >> 6;
        const int Q0  = 4 * h2;
        const float* xB = x + ((size_t)(b * 64 + c) * 512 + hb * 8) * 512
                            + wt * 16 + blk * 8;
        const float* tB = twm + c * 64;

        float M[8][4];
        {
            f4 Ph[8];
#pragma unroll
            for (int i = 0; i < 8; ++i) Ph[i] = *(const f4*)(xB + i * 512);
#pragma unroll
            for (int qq = 0; qq < 4; ++qq) {
                f4 Th = *(const f4*)(tB + (Q0 + qq) * 8);
#pragma unroll
                for (int i = 0; i < 8; ++i) {
                    float s = Ph[i][0] * Th[0];
                    s = fmaf(Ph[i][1], Th[1], s);
                    s = fmaf(Ph[i][2], Th[2], s);
                    s = fmaf(Ph[i][3], Th[3], s);
                    M[i][qq] = s;
                }
            }
#pragma unroll
            for (int i = 0; i < 8; ++i) Ph[i] = *(const f4*)(xB + i * 512 + 4);
#pragma unroll
            for (int qq = 0; qq < 4; ++qq) {
                f4 Th = *(const f4*)(tB + (Q0 + qq) * 8 + 4);
#pragma unroll
                for (int i = 0; i < 8; ++i) {
                    float s = M[i][qq];
                    s = fmaf(Ph[i][0], Th[0], s);
                    s = fmaf(Ph[i][1], Th[1], s);
                    s = fmaf(Ph[i][2], Th[2], s);
                    s = fmaf(Ph[i][3], Th[3], s);
                    M[i][qq] = s;
                }
            }
        }
        const int cg = c >> 3, c7 = c & 7;
#pragma unroll
        for (int p = 0; p < 8; ++p) {
            f4 a = *(const f4*)(tB + p * 8);
            f4 d = *(const f4*)(tB + p * 8 + 4);
            const int px0 = p * 16 + blk * 8;
#pragma unroll
            for (int qq = 0; qq < 4; ++qq) {
                const int q = Q0 + qq;
                float s = a[0] * M[0][qq];
                s = fmaf(a[1], M[1][qq], s);
                s = fmaf(a[2], M[2][qq], s);
                s = fmaf(a[3], M[3][qq], s);
                s = fmaf(d[0], M[4][qq], s);
                s = fmaf(d[1], M[5][qq], s);
                s = fmaf(d[2], M[6][qq], s);
                s = fmaf(d[3], M[7][qq], s);
                _Float16 hv = (_Float16)s;
                const int idx = ((cg ^ q ^ (blk << 2)) << 3) | c7;  // px&7==q
                *(_Float16*)&ysf[px0 + q][idx] = hv;
            }
        }
    }

    // ---- W fragments (single fp16) in registers ----
    h8 w1f[2], w2f[2];
    {
        const float* p1 = w1 + (16 * wv + li) * 64 + lg * 8;
        const float* p2 = w2 + (16 * wv + li) * 64 + lg * 8;
#pragma unroll
        for (int kk = 0; kk < 2; ++kk) {
            f4 a = *(const f4*)(p1 + kk * 32);
            f4 d = *(const f4*)(p1 + kk * 32 + 4);
            h8 f;
#pragma unroll
            for (int q = 0; q < 4; ++q) { f[q] = (_Float16)a[q]; f[4 + q] = (_Float16)d[q]; }
            w1f[kk] = f;
            a = *(const f4*)(p2 + kk * 32);
            d = *(const f4*)(p2 + kk * 32 + 4);
#pragma unroll
            for (int q = 0; q < 4; ++q) { f[q] = (_Float16)a[q]; f[4 + q] = (_Float16)d[q]; }
            w2f[kk] = f;
        }
    }
    const int o0 = 16 * wv + 4 * lg;
    const f4 b1v = *(const f4*)(b1 + o0);
    const float b2s = b2[16 * wv + li];
    const int sg0 = ((lg       ^ l7 ^ lb3) << 3);
    const int sg1 = (((4 + lg) ^ l7 ^ lb3) << 3);
    const int go  = o0 >> 3, co = 4 * (lg & 1);
    const int ch  = 16 * wv + li;
    const int cgE = ch >> 3, c7E = li & 7;

    __syncthreads();

    // ---- GEMM1: H = relu(W1 * Y + b1) (A=W1 f16, B=Y f16) ----
    f32x4 acc[8];
#pragma unroll
    for (int j = 0; j < 8; ++j) acc[j] = (f32x4){0.f, 0.f, 0.f, 0.f};
#pragma unroll
    for (int j = 0; j < 8; ++j) {
        const int row = 16 * j + li;
        h8 bh0 = *(const h8*)&ysf[row][sg0];
        h8 bh1 = *(const h8*)&ysf[row][sg1];
        acc[j] = __builtin_amdgcn_mfma_f32_16x16x32_f16(w1f[0], bh0, acc[j], 0, 0, 0);
        acc[j] = __builtin_amdgcn_mfma_f32_16x16x32_f16(w1f[1], bh1, acc[j], 0, 0, 0);
    }
#pragma unroll
    for (int j = 0; j < 8; ++j) {
        const int px = 16 * j + li;
        const int idx = ((go ^ l7 ^ lb3) << 3) + co;
        _Float16 h0 = (_Float16)fmaxf(acc[j][0] + b1v[0], 0.f);
        _Float16 h1 = (_Float16)fmaxf(acc[j][1] + b1v[1], 0.f);
        _Float16 h2v = (_Float16)fmaxf(acc[j][2] + b1v[2], 0.f);
        _Float16 h3 = (_Float16)fmaxf(acc[j][3] + b1v[3], 0.f);
        union { _Float16 h[2]; unsigned u; } p01, p23;
        p01.h[0] = h0; p01.h[1] = h1;
        p23.h[0] = h2v; p23.h[1] = h3;
        *(unsigned*)&hsf[px][idx]     = p01.u;
        *(unsigned*)&hsf[px][idx + 2] = p23.u;
    }
    __syncthreads();

    // ---- GEMM2 SWAPPED (A=H-frag, B=W2-frag): D[px][channel] ----
#pragma unroll
    for (int j = 0; j < 8; ++j) acc[j] = (f32x4){0.f, 0.f, 0.f, 0.f};
#pragma unroll
    for (int j = 0; j < 8; ++j) {
        const int row = 16 * j + li;
        h8 ah0 = *(const h8*)&hsf[row][sg0];
        h8 ah1 = *(const h8*)&hsf[row][sg1];
        acc[j] = __builtin_amdgcn_mfma_f32_16x16x32_f16(ah0, w2f[0], acc[j], 0, 0, 0);
        acc[j] = __builtin_amdgcn_mfma_f32_16x16x32_f16(ah1, w2f[1], acc[j], 0, 0, 0);
    }
    float* oB = out + ((size_t)(b * 64) + ch) * 262144
                + (size_t)(hb * 8) * 512 + wt * 16 + 4 * lg;
#pragma unroll
    for (int j = 0; j < 8; ++j) {
        f4 r;
#pragma unroll
        for (int r4 = 0; r4 < 4; ++r4) {
            const int pc = 4 * lg + r4;
            const int px = 16 * j + pc;
            const int idx = ((cgE ^ (pc & 7) ^ (((pc >> 3) & 1) << 2)) << 3) | c7E;
            float yv = (float)(*(const _Float16*)&ysf[px][idx]);
            float z = acc[j][r4] + b2s;
            float g = __builtin_amdgcn_rcpf(1.f + __expf(-z));
            r[r4] = yv * g;
        }
        *(f4*)(oB + (size_t)j * 512) = r;
    }
}

extern "C" void kernel_launch(void* const* d_in, const int* in_sizes, int n_in,
                              void* d_out, int out_size, void* d_ws, size_t ws_size,
                              hipStream_t stream) {
    (void)in_sizes; (void)n_in; (void)out_size; (void)d_ws; (void)ws_size;
    const float* x   = (const float*)d_in[0];
    const float* twm = (const float*)d_in[1];
    const float* w1  = (const float*)d_in[2];
    const float* b1  = (const float*)d_in[3];
    const float* w2  = (const float*)d_in[4];
    const float* b2  = (const float*)d_in[5];
    float* out = (float*)d_out;

    avif_mfma8<<<dim3(4 * 64 * 32), dim3(256), 0, stream>>>(x, twm, w1, b1, w2, b2, out);
}

// Round 9
// 170.217 us; speedup vs baseline: 1.7053x; 1.3662x over previous
//
#include <hip/hip_runtime.h>

typedef float f4 __attribute__((ext_vector_type(4)));
typedef __attribute__((ext_vector_type(4))) float f32x4;
typedef _Float16 h8 __attribute__((ext_vector_type(8)));

__device__ __forceinline__ void gload_lds16(const float* g, float* l) {
    __builtin_amdgcn_global_load_lds(
        (const __attribute__((address_space(1))) void*)g,
        (__attribute__((address_space(3))) void*)l, 16, 0, 0);
}

__global__ __launch_bounds__(256, 2)
void avif_pipe(const float* __restrict__ x, const float* __restrict__ twm,
               const float* __restrict__ w1, const float* __restrict__ b1,
               const float* __restrict__ w2, const float* __restrict__ b2,
               float* __restrict__ out)
{
    // xs: staged x tile. Granule (16B) layout: (c, r, qg) -> G = c*32 + ((r*4+qg)^(c&7))
    // (qg = 16B quarter of the 64B tile-row). Staged linearly by G; the XOR lives
    // in the per-lane GLOBAL source address (global_load_lds dest must be linear).
    __shared__ float xs[8192];        // 32 KB
    __shared__ ushort ysf[128][64];   // Y fp16, swizzled (16 KB)
    __shared__ ushort hsf[128][64];   // H fp16, swizzled (16 KB)  -> 64 KB total

    const int t = threadIdx.x;
    const int bid = blockIdx.x;       // 512 blocks: wc(2) x hb(64) x b(4)
    const int wc = bid & 1;
    const int hb = (bid >> 1) & 63;
    const int b  = bid >> 7;

    const int wv = t >> 6, lane = t & 63;
    const int li = lane & 15, lg = lane >> 4, l7 = li & 7;
    const int lb3 = (li >> 3) << 2;

    // ---- persistent staging source pointers (granule j*256 + t) ----
    const float* xslab = x + (((size_t)(b * 64)) * 512 + (size_t)hb * 8) * 512 + wc * 256;
    const float* gp[8];
#pragma unroll
    for (int j = 0; j < 8; ++j) {
        const int G = j * 256 + t;
        const int c = G >> 5;
        const int v = (G & 31) ^ (c & 7);
        const int r = v >> 2, qg = v & 3;
        gp[j] = xslab + (size_t)c * 262144 + r * 512 + qg * 4;
    }
    float* lbase = &xs[wv * 256];     // wave-uniform LDS base; + j*1024 per inst

    // ---- W fragments (fp16) + biases (round-8 verified) ----
    h8 w1f[2], w2f[2];
    {
        const float* p1 = w1 + (16 * wv + li) * 64 + lg * 8;
        const float* p2 = w2 + (16 * wv + li) * 64 + lg * 8;
#pragma unroll
        for (int kk = 0; kk < 2; ++kk) {
            f4 a = *(const f4*)(p1 + kk * 32);
            f4 d = *(const f4*)(p1 + kk * 32 + 4);
            h8 f;
#pragma unroll
            for (int q = 0; q < 4; ++q) { f[q] = (_Float16)a[q]; f[4 + q] = (_Float16)d[q]; }
            w1f[kk] = f;
            a = *(const f4*)(p2 + kk * 32);
            d = *(const f4*)(p2 + kk * 32 + 4);
#pragma unroll
            for (int q = 0; q < 4; ++q) { f[q] = (_Float16)a[q]; f[4 + q] = (_Float16)d[q]; }
            w2f[kk] = f;
        }
    }
    const int o0 = 16 * wv + 4 * lg;
    const f4 b1v = *(const f4*)(b1 + o0);
    const float b2s = b2[16 * wv + li];
    const int sg0 = ((lg       ^ l7 ^ lb3) << 3);
    const int sg1 = (((4 + lg) ^ l7 ^ lb3) << 3);
    const int go  = o0 >> 3, co = 4 * (lg & 1);
    const int ch  = 16 * wv + li;
    const int cgE = ch >> 3, c7E = li & 7;

    // ---- transform identity (lane pair shares (c,blk); q-partitioned) ----
    const int pid = t >> 1, h2 = t & 1;
    const int c   = pid & 63, blk = pid >> 6, Q0 = 4 * h2;
    const float* tB = twm + c * 64;
    const int sc = c * 128, swc = c & 7;     // float base / XOR key in xs
    const int cg = c >> 3, c7 = c & 7;

    // ================= prologue: stage tile 0 =================
#pragma unroll
    for (int j = 0; j < 8; ++j) gload_lds16(gp[j], lbase + j * 1024);
    asm volatile("s_waitcnt vmcnt(0)" ::: "memory");
    __syncthreads();

    for (int tile = 0; tile < 16; ++tile) {
        const int wt = wc * 16 + tile;

        // ---- transform: xs -> M -> Y -> ysf (fp16, swizzled) ----
        {
            float M[8][4];
            {
                f4 Ph[8];
#pragma unroll
                for (int i = 0; i < 8; ++i)
                    Ph[i] = *(const f4*)&xs[sc + ((i * 4 + blk * 2) ^ swc) * 4];
#pragma unroll
                for (int qq = 0; qq < 4; ++qq) {
                    f4 Th = *(const f4*)(tB + (Q0 + qq) * 8);
#pragma unroll
                    for (int i = 0; i < 8; ++i) {
                        float s = Ph[i][0] * Th[0];
                        s = fmaf(Ph[i][1], Th[1], s);
                        s = fmaf(Ph[i][2], Th[2], s);
                        s = fmaf(Ph[i][3], Th[3], s);
                        M[i][qq] = s;
                    }
                }
#pragma unroll
                for (int i = 0; i < 8; ++i)
                    Ph[i] = *(const f4*)&xs[sc + ((i * 4 + blk * 2 + 1) ^ swc) * 4];
#pragma unroll
                for (int qq = 0; qq < 4; ++qq) {
                    f4 Th = *(const f4*)(tB + (Q0 + qq) * 8 + 4);
#pragma unroll
                    for (int i = 0; i < 8; ++i) {
                        float s = M[i][qq];
                        s = fmaf(Ph[i][0], Th[0], s);
                        s = fmaf(Ph[i][1], Th[1], s);
                        s = fmaf(Ph[i][2], Th[2], s);
                        s = fmaf(Ph[i][3], Th[3], s);
                        M[i][qq] = s;
                    }
                }
            }
#pragma unroll
            for (int p = 0; p < 8; ++p) {
                f4 a = *(const f4*)(tB + p * 8);
                f4 d = *(const f4*)(tB + p * 8 + 4);
                const int px0 = p * 16 + blk * 8;
#pragma unroll
                for (int qq = 0; qq < 4; ++qq) {
                    const int q = Q0 + qq;
                    float s = a[0] * M[0][qq];
                    s = fmaf(a[1], M[1][qq], s);
                    s = fmaf(a[2], M[2][qq], s);
                    s = fmaf(a[3], M[3][qq], s);
                    s = fmaf(d[0], M[4][qq], s);
                    s = fmaf(d[1], M[5][qq], s);
                    s = fmaf(d[2], M[6][qq], s);
                    s = fmaf(d[3], M[7][qq], s);
                    const int idx = ((cg ^ q ^ (blk << 2)) << 3) | c7;
                    *(_Float16*)&ysf[px0 + q][idx] = (_Float16)s;
                }
            }
        }
        __syncthreads();   // B1: ysf ready, xs consumed

        // ---- issue next tile's staging (drains under GEMM1) ----
        if (tile < 15) {
#pragma unroll
            for (int j = 0; j < 8; ++j)
                gload_lds16(gp[j] + (tile + 1) * 16, lbase + j * 1024);
        }

        // ---- GEMM1: H = relu(W1 * Y + b1) ----
        f32x4 acc[8];
#pragma unroll
        for (int j = 0; j < 8; ++j) acc[j] = (f32x4){0.f, 0.f, 0.f, 0.f};
#pragma unroll
        for (int j = 0; j < 8; ++j) {
            const int row = 16 * j + li;
            h8 bh0 = *(const h8*)&ysf[row][sg0];
            h8 bh1 = *(const h8*)&ysf[row][sg1];
            acc[j] = __builtin_amdgcn_mfma_f32_16x16x32_f16(w1f[0], bh0, acc[j], 0, 0, 0);
            acc[j] = __builtin_amdgcn_mfma_f32_16x16x32_f16(w1f[1], bh1, acc[j], 0, 0, 0);
        }
#pragma unroll
        for (int j = 0; j < 8; ++j) {
            const int px = 16 * j + li;
            const int idx = ((go ^ l7 ^ lb3) << 3) + co;
            union { _Float16 h[2]; unsigned u; } p01, p23;
            p01.h[0] = (_Float16)fmaxf(acc[j][0] + b1v[0], 0.f);
            p01.h[1] = (_Float16)fmaxf(acc[j][1] + b1v[1], 0.f);
            p23.h[0] = (_Float16)fmaxf(acc[j][2] + b1v[2], 0.f);
            p23.h[1] = (_Float16)fmaxf(acc[j][3] + b1v[3], 0.f);
            *(unsigned*)&hsf[px][idx]     = p01.u;
            *(unsigned*)&hsf[px][idx + 2] = p23.u;
        }
        asm volatile("s_waitcnt vmcnt(0)" ::: "memory");
        __syncthreads();   // B2: hsf ready, xs(t+1) landed

        // ---- GEMM2 swapped (A=H, B=W2): D[px][channel]; epilogue f4 stores ----
#pragma unroll
        for (int j = 0; j < 8; ++j) acc[j] = (f32x4){0.f, 0.f, 0.f, 0.f};
#pragma unroll
        for (int j = 0; j < 8; ++j) {
            const int row = 16 * j + li;
            h8 ah0 = *(const h8*)&hsf[row][sg0];
            h8 ah1 = *(const h8*)&hsf[row][sg1];
            acc[j] = __builtin_amdgcn_mfma_f32_16x16x32_f16(ah0, w2f[0], acc[j], 0, 0, 0);
            acc[j] = __builtin_amdgcn_mfma_f32_16x16x32_f16(ah1, w2f[1], acc[j], 0, 0, 0);
        }
        float* oB = out + ((size_t)(b * 64) + ch) * 262144
                    + (size_t)(hb * 8) * 512 + wt * 16 + 4 * lg;
#pragma unroll
        for (int j = 0; j < 8; ++j) {
            f4 r;
#pragma unroll
            for (int r4 = 0; r4 < 4; ++r4) {
                const int pc = 4 * lg + r4;
                const int px = 16 * j + pc;
                const int idx = ((cgE ^ (pc & 7) ^ (((pc >> 3) & 1) << 2)) << 3) | c7E;
                float yv = (float)(*(const _Float16*)&ysf[px][idx]);
                float z = acc[j][r4] + b2s;
                float g = __builtin_amdgcn_rcpf(1.f + __expf(-z));
                r[r4] = yv * g;
            }
            *(f4*)(oB + (size_t)j * 512) = r;
        }
        __syncthreads();   // B3: ysf/hsf consumed; safe to overwrite next iter
    }
}

extern "C" void kernel_launch(void* const* d_in, const int* in_sizes, int n_in,
                              void* d_out, int out_size, void* d_ws, size_t ws_size,
                              hipStream_t stream) {
    (void)in_sizes; (void)n_in; (void)out_size; (void)d_ws; (void)ws_size;
    const float* x   = (const float*)d_in[0];
    const float* twm = (const float*)d_in[1];
    const float* w1  = (const float*)d_in[2];
    const float* b1  = (const float*)d_in[3];
    const float* w2  = (const float*)d_in[4];
    const float* b2  = (const float*)d_in[5];
    float* out = (float*)d_out;

    avif_pipe<<<dim3(512), dim3(256), 0, stream>>>(x, twm, w1, b1, w2, b2, out);
}